// Round 9
// baseline (113.083 us; speedup 1.0000x reference)
//
#include <hip/hip_runtime.h>

// Problem constants (fixed by setup_inputs: N=8192, D=8, fp32).
constexpr int N = 8192;
constexpr int BLK = 256;            // threads per block
constexpr int IPT = 8;              // i-rows per thread, in NAMED registers
constexpr int ITILE = BLK * IPT;    // 2048 i-rows per block
constexpr int NIT = N / ITILE;      // 4 i-tiles
constexpr int JCHUNK = 64;          // j-rows per block (read via uniform loads)
constexpr int JCH = N / JCHUNK;     // 128 -> grid 1024 = 4 blocks/CU

typedef float f32x2 __attribute__((ext_vector_type(2)));
typedef float f32x4 __attribute__((ext_vector_type(4)));

// Packed fp32 add: 2 diffs per instruction. i-rows are pre-negated in
// registers, so d = Mj + (-Mi) and dominance(i over j) <=> max_d(d) < 0.
__device__ __forceinline__ f32x2 pk_add(f32x2 a, f32x2 b) {
  f32x2 r;
  asm("v_pk_add_f32 %0, %1, %2" : "=v"(r) : "v"(a), "v"(b));
  return r;
}
__device__ __forceinline__ float max3f(float a, float b, float c) {
  float r;
  asm("v_max3_f32 %0, %1, %2, %3" : "=v"(r) : "v"(a), "v"(b), "v"(c));
  return r;
}
__device__ __forceinline__ float max2f(float a, float b) {
  float r;
  asm("v_max_f32 %0, %1, %2" : "=v"(r) : "v"(a), "v"(b));
  return r;
}

// counts[m*N + i] = #{ j : M[i,d] > M[j,d] for all d }
// Strict dominance: max_d(M[j,d] - M[i,d]) < 0. Ties give +/-0.0 -> max >=
// -0.0 -> (<0) false -> rejected; self gives 0 -> rejected. Same exact
// arithmetic as the validated min-diff form (absmax 0.0, R1-R8).
// R9: NO LDS in this kernel (the R6-R8 wall was the shared per-CU LDS pipe);
// j-rows are block-uniform loads (scalar/L1 path), i-rows in named registers
// (arrays got demoted at IPT=8 in R5/R8 -> VGPR_Count 52/56).
__global__ __launch_bounds__(BLK, 4) void dom_count_kernel(
    const float* __restrict__ X, const float* __restrict__ Xh,
    int* __restrict__ counts) {
  const float* __restrict__ M = (blockIdx.z == 0) ? X : Xh;
  int* cnt_out = counts + blockIdx.z * N;

  const int tid = threadIdx.x;
  const int ibase = blockIdx.x * ITILE + tid;   // rows ibase + p*BLK

  // my 8 i-rows, NEGATED, in named registers (nothing for regalloc to demote)
#define LOADROW(p)                                                         \
  f32x4 na##p, nb##p;                                                      \
  {                                                                        \
    const f32x4* Mi =                                                      \
        reinterpret_cast<const f32x4*>(M + (size_t)(ibase + p * BLK) * 8); \
    na##p = -Mi[0];                                                        \
    nb##p = -Mi[1];                                                        \
  }
  LOADROW(0) LOADROW(1) LOADROW(2) LOADROW(3)
  LOADROW(4) LOADROW(5) LOADROW(6) LOADROW(7)
#undef LOADROW

  int c0 = 0, c1 = 0, c2 = 0, c3 = 0, c4 = 0, c5 = 0, c6 = 0, c7 = 0;

  const float* __restrict__ Mj = M + (size_t)(blockIdx.y * JCHUNK) * 8;
  for (int j = 0; j < JCHUNK; ++j) {
    // block-uniform address -> scalar (s_load) or single-line L1 load
    const f32x4 a = *reinterpret_cast<const f32x4*>(Mj + j * 8);
    const f32x4 b = *reinterpret_cast<const f32x4*>(Mj + j * 8 + 4);
#define PAIR(p)                                              \
  {                                                          \
    const f32x2 d01 = pk_add(a.xy, na##p.xy);                \
    const f32x2 d23 = pk_add(a.zw, na##p.zw);                \
    const f32x2 d45 = pk_add(b.xy, nb##p.xy);                \
    const f32x2 d67 = pk_add(b.zw, nb##p.zw);                \
    const float t0 = max3f(d01.x, d01.y, d23.x);             \
    const float t1 = max3f(d23.y, d45.x, d45.y);             \
    const float t2 = max3f(d67.x, d67.y, t0);                \
    c##p += (max2f(t1, t2) < 0.0f) ? 1 : 0;                  \
  }
    PAIR(0) PAIR(1) PAIR(2) PAIR(3) PAIR(4) PAIR(5) PAIR(6) PAIR(7)
#undef PAIR
  }

  atomicAdd(&cnt_out[ibase + 0 * BLK], c0);
  atomicAdd(&cnt_out[ibase + 1 * BLK], c1);
  atomicAdd(&cnt_out[ibase + 2 * BLK], c2);
  atomicAdd(&cnt_out[ibase + 3 * BLK], c3);
  atomicAdd(&cnt_out[ibase + 4 * BLK], c4);
  atomicAdd(&cnt_out[ibase + 5 * BLK], c5);
  atomicAdd(&cnt_out[ibase + 6 * BLK], c6);
  atomicAdd(&cnt_out[ibase + 7 * BLK], c7);
}

// --- Finalize, stage 1: privatized histograms (R3-proven) -------------------
// sum_k |sort(a)_k - sort(b)_k| == sum_t |#{a<=t} - #{b<=t}|; histogram +1 for
// X counts, -1 for Xh counts. 16 blocks privatize hot-bin contention.
constexpr int HB = 16;
__global__ __launch_bounds__(1024) void hist_partial_kernel(
    const int* __restrict__ counts, int* __restrict__ ghist) {
  __shared__ int lhist[N];  // 32 KB
  const int tid = threadIdx.x;
  for (int q = tid; q < N; q += 1024) lhist[q] = 0;
  __syncthreads();

  const int k = blockIdx.x * (2 * N / HB) + tid;  // 1024 values per block
  const int v = counts[k];
  atomicAdd(&lhist[v], (k < N) ? 1 : -1);
  __syncthreads();

#pragma unroll
  for (int q = 0; q < N / 1024; ++q) {
    const int bin = tid * (N / 1024) + q;
    const int h = lhist[bin];
    if (h != 0) atomicAdd(&ghist[bin], h);
  }
}

// --- Finalize, stage 2: scan + abs-sum (one small block, R3-proven) ---------
__global__ __launch_bounds__(1024) void finalize_kernel(
    const int* __restrict__ ghist, float* __restrict__ out) {
  __shared__ int wsum[16];
  __shared__ int wexc[16];
  __shared__ int wabs[16];

  const int tid = threadIdx.x;
  const int lane = tid & 63;
  const int wid = tid >> 6;

  int local[8];
  int s = 0;
#pragma unroll
  for (int q = 0; q < 8; ++q) {
    local[q] = ghist[tid * 8 + q];
    s += local[q];
  }

  int incl = s;  // wave-inclusive scan of per-thread sums
#pragma unroll
  for (int off = 1; off < 64; off <<= 1) {
    const int v = __shfl_up(incl, off);
    if (lane >= off) incl += v;
  }
  if (lane == 63) wsum[wid] = incl;
  __syncthreads();

  if (tid == 0) {
    int acc = 0;
#pragma unroll
    for (int w = 0; w < 16; ++w) { wexc[w] = acc; acc += wsum[w]; }
  }
  __syncthreads();

  int run = wexc[wid] + (incl - s);  // exclusive prefix of my 8-bin chunk
  int acc = 0;
#pragma unroll
  for (int q = 0; q < 8; ++q) {
    run += local[q];
    acc += (run < 0) ? -run : run;
  }

#pragma unroll
  for (int off = 32; off > 0; off >>= 1) acc += __shfl_down(acc, off);
  if (lane == 0) wabs[wid] = acc;
  __syncthreads();

  if (tid == 0) {
    int total = 0;
#pragma unroll
    for (int w = 0; w < 16; ++w) total += wabs[w];
    // result = total / (N-1) / N
    out[0] = (float)((double)total / ((double)(N - 1) * (double)N));
  }
}

extern "C" void kernel_launch(void* const* d_in, const int* in_sizes, int n_in,
                              void* d_out, int out_size, void* d_ws, size_t ws_size,
                              hipStream_t stream) {
  const float* X = (const float*)d_in[0];
  const float* Xh = (const float*)d_in[1];
  float* out = (float*)d_out;
  int* counts = (int*)d_ws;        // 2N ints
  int* ghist = counts + 2 * N;     // N ints, contiguous

  hipMemsetAsync(counts, 0, 3 * N * sizeof(int), stream);

  dim3 grid(NIT, JCH, 2);
  dom_count_kernel<<<grid, BLK, 0, stream>>>(X, Xh, counts);
  hist_partial_kernel<<<HB, 1024, 0, stream>>>(counts, ghist);
  finalize_kernel<<<1, 1024, 0, stream>>>(ghist, out);
}

// Round 11
// 104.273 us; speedup vs baseline: 1.0845x; 1.0845x over previous
//
#include <hip/hip_runtime.h>

// Problem constants (fixed by setup_inputs: N=8192, D=8, fp32).
constexpr int N = 8192;
constexpr int BLK = 256;           // threads per block (4 waves)
constexpr int JSPLIT = 32;         // j-range splits -> grid 32*32*2 = 2048 = 8 blk/CU
constexpr int JSEG = N / JSPLIT;   // 256 j-rows per block

typedef float f32x4 __attribute__((ext_vector_type(4)));
typedef uint32_t u32x16 __attribute__((ext_vector_type(16)));

// j-rows through the SCALAR path: one s_load_dwordx16 = 2 rows.
#define SLOAD16(dst, base, immstr) \
  asm volatile("s_load_dwordx16 %0, %1, " immstr : "=s"(dst) : "s"(base))

// One j-row vs 64 i-rows (one per lane): chain 8 v_cmpx — each compare ANDs
// into EXEC (inactive lanes stay inactive) — then cnt+=1 on survivors and
// restore EXEC. 9 VALU + 1 SALU per 64 pairs.
// Strict dominance: X[i,d] > X[j,d] for all d <=> all (s_j < v_i).
// Ties/self fail strict lt -> rejected (semantics validated in R1-R9).
#define DOMSTEP(r, k0)                                                       \
  asm volatile(                                                              \
      "v_cmpx_lt_f32 vcc, %[a0], %[x0]\n\t"                                  \
      "v_cmpx_lt_f32 vcc, %[a1], %[x1]\n\t"                                  \
      "v_cmpx_lt_f32 vcc, %[a2], %[x2]\n\t"                                  \
      "v_cmpx_lt_f32 vcc, %[a3], %[x3]\n\t"                                  \
      "v_cmpx_lt_f32 vcc, %[a4], %[x4]\n\t"                                  \
      "v_cmpx_lt_f32 vcc, %[a5], %[x5]\n\t"                                  \
      "v_cmpx_lt_f32 vcc, %[a6], %[x6]\n\t"                                  \
      "v_cmpx_lt_f32 vcc, %[a7], %[x7]\n\t"                                  \
      "v_add_u32 %[c], 1, %[c]\n\t"                                          \
      "s_mov_b64 exec, %[sv]"                                                \
      : [c] "+v"(cnt)                                                        \
      : [a0] "s"(r[k0 + 0]), [a1] "s"(r[k0 + 1]), [a2] "s"(r[k0 + 2]),       \
        [a3] "s"(r[k0 + 3]), [a4] "s"(r[k0 + 4]), [a5] "s"(r[k0 + 5]),       \
        [a6] "s"(r[k0 + 6]), [a7] "s"(r[k0 + 7]), [x0] "v"(xi0),             \
        [x1] "v"(xi1), [x2] "v"(xi2), [x3] "v"(xi3), [x4] "v"(xi4),          \
        [x5] "v"(xi5), [x6] "v"(xi6), [x7] "v"(xi7), [sv] "s"(sv)            \
      : "vcc")

// counts[m*N + i] = #{ j : M[i,d] > M[j,d] for all d }
__global__ __launch_bounds__(BLK, 4) void dom_count_kernel(
    const float* __restrict__ X, const float* __restrict__ Xh,
    int* __restrict__ counts) {
  const float* __restrict__ M = (blockIdx.z == 0) ? X : Xh;
  int* cnt_out = counts + blockIdx.z * N;

  const int i = blockIdx.x * BLK + threadIdx.x;

  // my i-row in 8 lane registers
  const f32x4* Mi = reinterpret_cast<const f32x4*>(M + (size_t)i * 8);
  const f32x4 ra = Mi[0];
  const f32x4 rb = Mi[1];
  const float xi0 = ra.x, xi1 = ra.y, xi2 = ra.z, xi3 = ra.w;
  const float xi4 = rb.x, xi5 = rb.y, xi6 = rb.z, xi7 = rb.w;

  // save full exec once (no divergence: every size divides exactly)
  uint64_t sv;
  asm volatile("s_mov_b64 %0, exec" : "=s"(sv));

  int cnt = 0;
  const float* jb = M + (size_t)(blockIdx.y * JSEG) * 8;
  for (int jj = 0; jj < JSEG; jj += 8) {
    u32x16 q0, q1, q2, q3;
    const float* gb = jb + (size_t)jj * 8;
    SLOAD16(q0, gb, "0x0");
    SLOAD16(q1, gb, "0x40");
    SLOAD16(q2, gb, "0x80");
    SLOAD16(q3, gb, "0xC0");
    // R11 FIX (the R10 corruption): thread q0..q3 THROUGH the waitcnt as
    // "+s" in/outs. Every element extraction below is now data-dependent on
    // this block's OUTPUT, so the compiler cannot hoist sub-register copies
    // above the wait (s_load is async; R10 read in-flight SGPRs).
    asm volatile("s_waitcnt lgkmcnt(0)"
                 : "+s"(q0), "+s"(q1), "+s"(q2), "+s"(q3));
    DOMSTEP(q0, 0);
    DOMSTEP(q0, 8);
    DOMSTEP(q1, 0);
    DOMSTEP(q1, 8);
    DOMSTEP(q2, 0);
    DOMSTEP(q2, 8);
    DOMSTEP(q3, 0);
    DOMSTEP(q3, 8);
  }

  atomicAdd(&cnt_out[i], cnt);
}

// --- Finalize, stage 1: privatized histograms (R3-proven) -------------------
// sum_k |sort(a)_k - sort(b)_k| == sum_t |#{a<=t} - #{b<=t}|; histogram +1 for
// X counts, -1 for Xh counts. 16 blocks privatize hot-bin contention.
constexpr int HB = 16;
__global__ __launch_bounds__(1024) void hist_partial_kernel(
    const int* __restrict__ counts, int* __restrict__ ghist) {
  __shared__ int lhist[N];  // 32 KB
  const int tid = threadIdx.x;
  for (int q = tid; q < N; q += 1024) lhist[q] = 0;
  __syncthreads();

  const int k = blockIdx.x * (2 * N / HB) + tid;  // 1024 values per block
  const int v = counts[k];
  atomicAdd(&lhist[v], (k < N) ? 1 : -1);
  __syncthreads();

#pragma unroll
  for (int q = 0; q < N / 1024; ++q) {
    const int bin = tid * (N / 1024) + q;
    const int h = lhist[bin];
    if (h != 0) atomicAdd(&ghist[bin], h);
  }
}

// --- Finalize, stage 2: scan + abs-sum (one small block, R3-proven) ---------
__global__ __launch_bounds__(1024) void finalize_kernel(
    const int* __restrict__ ghist, float* __restrict__ out) {
  __shared__ int wsum[16];
  __shared__ int wexc[16];
  __shared__ int wabs[16];

  const int tid = threadIdx.x;
  const int lane = tid & 63;
  const int wid = tid >> 6;

  int local[8];
  int s = 0;
#pragma unroll
  for (int q = 0; q < 8; ++q) {
    local[q] = ghist[tid * 8 + q];
    s += local[q];
  }

  int incl = s;  // wave-inclusive scan of per-thread sums
#pragma unroll
  for (int off = 1; off < 64; off <<= 1) {
    const int v = __shfl_up(incl, off);
    if (lane >= off) incl += v;
  }
  if (lane == 63) wsum[wid] = incl;
  __syncthreads();

  if (tid == 0) {
    int acc = 0;
#pragma unroll
    for (int w = 0; w < 16; ++w) { wexc[w] = acc; acc += wsum[w]; }
  }
  __syncthreads();

  int run = wexc[wid] + (incl - s);  // exclusive prefix of my 8-bin chunk
  int acc = 0;
#pragma unroll
  for (int q = 0; q < 8; ++q) {
    run += local[q];
    acc += (run < 0) ? -run : run;
  }

#pragma unroll
  for (int off = 32; off > 0; off >>= 1) acc += __shfl_down(acc, off);
  if (lane == 0) wabs[wid] = acc;
  __syncthreads();

  if (tid == 0) {
    int total = 0;
#pragma unroll
    for (int w = 0; w < 16; ++w) total += wabs[w];
    // result = total / (N-1) / N
    out[0] = (float)((double)total / ((double)(N - 1) * (double)N));
  }
}

extern "C" void kernel_launch(void* const* d_in, const int* in_sizes, int n_in,
                              void* d_out, int out_size, void* d_ws, size_t ws_size,
                              hipStream_t stream) {
  const float* X = (const float*)d_in[0];
  const float* Xh = (const float*)d_in[1];
  float* out = (float*)d_out;
  int* counts = (int*)d_ws;        // 2N ints
  int* ghist = counts + 2 * N;     // N ints, contiguous

  hipMemsetAsync(counts, 0, 3 * N * sizeof(int), stream);

  dim3 grid(N / BLK, JSPLIT, 2);
  dom_count_kernel<<<grid, BLK, 0, stream>>>(X, Xh, counts);
  hist_partial_kernel<<<HB, 1024, 0, stream>>>(counts, ghist);
  finalize_kernel<<<1, 1024, 0, stream>>>(ghist, out);
}